// Round 10
// baseline (23.863 us; speedup 1.0000x reference)
//
#include <hip/hip_runtime.h>

// YOLO loss: S=7, B=2, C=20, LAMBDA_COORD=5, LAMBDA_NOOBJ=0.5, N=8192.
// pred: (8192, 49*30) f32, target: (8192, 49*25) f32, out: scalar f32.
// M = 401408 cells = 3136 blocks x 128 cells (2 chunks of 64).
// Round-10: barrier-free double-buffered DMA pipeline. One wave per
// block stages AND consumes -> no __syncthreads. Issue 15 global_load_lds
// for chunk A, 15 for chunk B, then counted s_waitcnt vmcnt(15) (A done,
// B in flight), compute A, vmcnt(0), compute B. Memory pipe never drains
// during compute. Two-dispatch structure final (rounds 4/5/7: intra-kernel
// cross-XCD handshakes cost 2-4x the dispatch bubble).

#define NBATCH  8192
#define PSTRIDE 30
#define TSTRIDE 25
#define TPB     64
#define CPB     128            // cells per block = 2 chunks x 64
#define NBLOCKS 3136           // 401408 / 128
#define PBYTES  (64 * PSTRIDE * 4)   // 7680 B per chunk
#define TBYTES  (64 * TSTRIDE * 4)   // 6400 B per chunk

__device__ __forceinline__ void gll16(const void* g, void* l) {
    __builtin_amdgcn_global_load_lds(
        (const __attribute__((address_space(1))) void*)g,
        (__attribute__((address_space(3))) void*)l,
        16, 0, 0);
}

__device__ __forceinline__ float cell_loss(const float* __restrict__ p,
                                           const float* __restrict__ t,
                                           int cell)
{
    float gy = (float)(cell / 7);
    float gx = (float)(cell % 7);
    const float invS = 1.0f / 7.0f;

    float t0 = t[0], tx = t[1], ty = t[2], tw = t[3], th = t[4];
    float objf   = (t0 == 1.0f) ? 1.0f : 0.0f;
    float noobjf = (t0 == 0.0f) ? 1.0f : 0.0f;

    float tcx = (gx + tx) * invS, tcy = (gy + ty) * invS;
    float tx1 = tcx - tw * 0.5f, ty1 = tcy - th * 0.5f;
    float tx2 = tcx + tw * 0.5f, ty2 = tcy + th * 0.5f;
    float area_t = (tx2 - tx1) * (ty2 - ty1);

    float conf[2], bx[2], by[2], bw[2], bh[2], iou[2];
    #pragma unroll
    for (int b = 0; b < 2; ++b) {
        conf[b] = p[b * 5 + 0];
        bx[b]   = p[b * 5 + 1];
        by[b]   = p[b * 5 + 2];
        bw[b]   = p[b * 5 + 3];
        bh[b]   = p[b * 5 + 4];
        float ax = fabsf(bx[b]), ay = fabsf(by[b]);
        float aw = fabsf(bw[b]), ah = fabsf(bh[b]);
        float cx = (gx + ax) * invS, cy = (gy + ay) * invS;
        float x1 = cx - aw * 0.5f, y1 = cy - ah * 0.5f;
        float x2 = cx + aw * 0.5f, y2 = cy + ah * 0.5f;
        float ltx = fmaxf(x1, tx1), lty = fmaxf(y1, ty1);
        float rbx = fminf(x2, tx2), rby = fminf(y2, ty2);
        float wx = fmaxf(rbx - ltx, 0.0f);
        float wy = fmaxf(rby - lty, 0.0f);
        float inter = wx * wy;
        float area_p = (x2 - x1) * (y2 - y1);
        iou[b] = inter / (area_p + area_t - inter);
    }

    int best = (iou[1] > iou[0]) ? 1 : 0;       // first index wins ties
    float miou = fmaxf(iou[0], iou[1]);

    float rc = conf[best];
    float rx = bx[best], ry = by[best], rw = bw[best], rh = bh[best];

    float dx = rx - tx, dy = ry - ty;
    float sw = sqrtf(fabsf(rw)) - sqrtf(fabsf(tw));
    float sh = sqrtf(fabsf(rh)) - sqrtf(fabsf(th));
    float loc = dx * dx + dy * dy + sw * sw + sh * sh;

    float oc = rc - miou;
    oc = oc * oc;

    float no = conf[0] * conf[0] + conf[1] * conf[1];

    float cls = 0.0f;
    #pragma unroll
    for (int k = 0; k < 20; ++k) {
        float d = p[10 + k] - t[5 + k];
        cls += d * d;
    }

    return objf * (5.0f * loc + oc + cls) + 0.5f * noobjf * no;
}

__global__ __launch_bounds__(TPB) void yolo_partial_kernel(
    const float* __restrict__ pred,
    const float* __restrict__ tgt,
    float* __restrict__ partials)
{
    __shared__ __align__(16) float sp[2][64 * PSTRIDE];   // 2 x 7680 B
    __shared__ __align__(16) float st[2][64 * TSTRIDE];   // 2 x 6400 B

    const int lane = threadIdx.x;
    const size_t cell0 = (size_t)blockIdx.x * CPB;

    const char* gp = (const char*)(pred + cell0 * PSTRIDE);
    const char* gt = (const char*)(tgt  + cell0 * TSTRIDE);

    // ---- issue chunk A: 8 + 7 = 15 vm instructions ----
    {
        char* lp = (char*)sp[0];
        #pragma unroll
        for (int s = 0; s < 7; ++s)
            gll16(gp + s * 1024 + lane * 16, lp + s * 1024 + lane * 16);
        if (lane < 32)   // 7680 - 7*1024 = 512 B
            gll16(gp + 7 * 1024 + lane * 16, lp + 7 * 1024 + lane * 16);
        char* lt = (char*)st[0];
        #pragma unroll
        for (int s = 0; s < 6; ++s)
            gll16(gt + s * 1024 + lane * 16, lt + s * 1024 + lane * 16);
        if (lane < 16)   // 6400 - 6*1024 = 256 B
            gll16(gt + 6 * 1024 + lane * 16, lt + 6 * 1024 + lane * 16);
    }
    asm volatile("" ::: "memory");     // pin A-issue before B-issue
    // ---- issue chunk B: 15 vm instructions ----
    {
        const char* gpb = gp + PBYTES;
        const char* gtb = gt + TBYTES;
        char* lp = (char*)sp[1];
        #pragma unroll
        for (int s = 0; s < 7; ++s)
            gll16(gpb + s * 1024 + lane * 16, lp + s * 1024 + lane * 16);
        if (lane < 32)
            gll16(gpb + 7 * 1024 + lane * 16, lp + 7 * 1024 + lane * 16);
        char* lt = (char*)st[1];
        #pragma unroll
        for (int s = 0; s < 6; ++s)
            gll16(gtb + s * 1024 + lane * 16, lt + s * 1024 + lane * 16);
        if (lane < 16)
            gll16(gtb + 6 * 1024 + lane * 16, lt + 6 * 1024 + lane * 16);
    }

    // ---- wait for A only (B's 15 stay in flight), compute A ----
    asm volatile("s_waitcnt vmcnt(15)" ::: "memory");
    __builtin_amdgcn_sched_barrier(0);
    float part = cell_loss(&sp[0][lane * PSTRIDE], &st[0][lane * TSTRIDE],
                           (int)((cell0 + lane) % 49));

    // ---- wait for B, compute B ----
    asm volatile("s_waitcnt vmcnt(0)" ::: "memory");
    __builtin_amdgcn_sched_barrier(0);
    part += cell_loss(&sp[1][lane * PSTRIDE], &st[1][lane * TSTRIDE],
                      (int)((cell0 + 64 + lane) % 49));

    // ---- wave reduce, one plain store per block ----
    #pragma unroll
    for (int off = 32; off > 0; off >>= 1)
        part += __shfl_down(part, off, 64);
    if (lane == 0)
        partials[blockIdx.x] = part;
}

__global__ __launch_bounds__(256) void yolo_final_kernel(
    const float* __restrict__ partials,
    float* __restrict__ out, float invN)
{
    const int tid = threadIdx.x;
    float s = 0.0f;
    #pragma unroll
    for (int k = 0; k < 13; ++k) {          // 13*256 = 3328 >= 3136
        int i = tid + k * 256;
        if (i < NBLOCKS) s += partials[i];
    }
    #pragma unroll
    for (int off = 32; off > 0; off >>= 1)
        s += __shfl_down(s, off, 64);
    __shared__ float ws[4];
    int lane = tid & 63, wid = tid >> 6;
    if (lane == 0) ws[wid] = s;
    __syncthreads();
    if (tid == 0)
        out[0] = (ws[0] + ws[1] + ws[2] + ws[3]) * invN;
}

extern "C" void kernel_launch(void* const* d_in, const int* in_sizes, int n_in,
                              void* d_out, int out_size, void* d_ws, size_t ws_size,
                              hipStream_t stream) {
    const float* pred = (const float*)d_in[0];
    const float* tgt  = (const float*)d_in[1];
    float* out = (float*)d_out;
    float* partials = (float*)d_ws;        // 3136 f32, fully overwritten

    yolo_partial_kernel<<<NBLOCKS, TPB, 0, stream>>>(pred, tgt, partials);
    yolo_final_kernel<<<1, 256, 0, stream>>>(partials, out, 1.0f / (float)NBATCH);
}

// Round 11
// 22.263 us; speedup vs baseline: 1.0719x; 1.0719x over previous
//
#include <hip/hip_runtime.h>

// YOLO loss: S=7, B=2, C=20, LAMBDA_COORD=5, LAMBDA_NOOBJ=0.5, N=8192.
// pred: (8192, 49*30) f32, target: (8192, 49*25) f32, out: scalar f32.
// M = 401408 cells = 3136 chunks of 128. BEST-KNOWN structure (round 9,
// 23.2 us): kernel 1 stages via __builtin_amdgcn_global_load_lds width=16
// (direct global->LDS DMA, no VGPR round-trip), one barrier, per-cell
// compute, block reduce, plain partial store. Kernel 2 sums partials
// (float4-vectorized). Two-dispatch structure is FINAL: rounds 4/5/7
// measured grid-sync=66us, spin-acquire=52us, ticket-RMW=90us vs 23us —
// every intra-kernel cross-XCD handshake costs 2-4x the dispatch bubble.
// Round 8/10 showed barrier-free / double-buffered variants are neutral:
// kernel 1 is BW-bound (~5 TB/s effective, ~80% of achievable; harness's
// 268MB poison-fill flushes L3 between replays so HBM is the floor).

#define NBATCH  8192
#define PSTRIDE 30
#define TSTRIDE 25
#define TPB     128
#define NCHUNKS 3136       // M / TPB

__device__ __forceinline__ void gll16(const void* g, void* l) {
    __builtin_amdgcn_global_load_lds(
        (const __attribute__((address_space(1))) void*)g,
        (__attribute__((address_space(3))) void*)l,
        16, 0, 0);
}

__global__ __launch_bounds__(TPB) void yolo_partial_kernel(
    const float* __restrict__ pred,
    const float* __restrict__ tgt,
    float* __restrict__ partials)
{
    __shared__ __align__(16) float sp[TPB * PSTRIDE];   // 15360 B
    __shared__ __align__(16) float st[TPB * TSTRIDE];   // 12800 B

    const int tid  = threadIdx.x;
    const int lane = tid & 63;
    const int wid  = tid >> 6;
    const size_t c0 = (size_t)blockIdx.x * TPB;

    // ---- stage pred: 15360 B = 15 x 1024B DMA segments (2 waves) ----
    const char* gpred = (const char*)(pred + c0 * PSTRIDE);
    char* lpred = (char*)sp;
    for (int s = wid; s < 15; s += 2)
        gll16(gpred + s * 1024 + lane * 16, lpred + s * 1024 + lane * 16);

    // ---- stage target: 12800 B = 12 x 1024B DMA + 512B tail ----
    const char* gtgt = (const char*)(tgt + c0 * TSTRIDE);
    char* ltgt = (char*)st;
    for (int s = wid; s < 12; s += 2)
        gll16(gtgt + s * 1024 + lane * 16, ltgt + s * 1024 + lane * 16);
    if (tid < 32)    // float4 indices 768..800 via ordinary path
        ((float4*)st)[768 + tid] = ((const float4*)gtgt)[768 + tid];

    __syncthreads();   // single drain: vmcnt(0) covers all DMA loads

    // ---- per-cell compute from LDS ----
    const float* p = sp + tid * PSTRIDE;
    const float* t = st + tid * TSTRIDE;

    int cell = (int)((c0 + tid) % 49);
    float gy = (float)(cell / 7);
    float gx = (float)(cell % 7);
    const float invS = 1.0f / 7.0f;

    float t0 = t[0], tx = t[1], ty = t[2], tw = t[3], th = t[4];
    float objf   = (t0 == 1.0f) ? 1.0f : 0.0f;
    float noobjf = (t0 == 0.0f) ? 1.0f : 0.0f;

    float tcx = (gx + tx) * invS, tcy = (gy + ty) * invS;
    float tx1 = tcx - tw * 0.5f, ty1 = tcy - th * 0.5f;
    float tx2 = tcx + tw * 0.5f, ty2 = tcy + th * 0.5f;
    float area_t = (tx2 - tx1) * (ty2 - ty1);

    float conf[2], bx[2], by[2], bw[2], bh[2], iou[2];
    #pragma unroll
    for (int b = 0; b < 2; ++b) {
        conf[b] = p[b * 5 + 0];
        bx[b]   = p[b * 5 + 1];
        by[b]   = p[b * 5 + 2];
        bw[b]   = p[b * 5 + 3];
        bh[b]   = p[b * 5 + 4];
        float ax = fabsf(bx[b]), ay = fabsf(by[b]);
        float aw = fabsf(bw[b]), ah = fabsf(bh[b]);
        float cx = (gx + ax) * invS, cy = (gy + ay) * invS;
        float x1 = cx - aw * 0.5f, y1 = cy - ah * 0.5f;
        float x2 = cx + aw * 0.5f, y2 = cy + ah * 0.5f;
        float ltx = fmaxf(x1, tx1), lty = fmaxf(y1, ty1);
        float rbx = fminf(x2, tx2), rby = fminf(y2, ty2);
        float wx = fmaxf(rbx - ltx, 0.0f);
        float wy = fmaxf(rby - lty, 0.0f);
        float inter = wx * wy;
        float area_p = (x2 - x1) * (y2 - y1);
        iou[b] = inter / (area_p + area_t - inter);
    }

    int best = (iou[1] > iou[0]) ? 1 : 0;       // first index wins ties
    float miou = fmaxf(iou[0], iou[1]);

    float rc = conf[best];
    float rx = bx[best], ry = by[best], rw = bw[best], rh = bh[best];

    float dx = rx - tx, dy = ry - ty;
    float sw = sqrtf(fabsf(rw)) - sqrtf(fabsf(tw));
    float sh = sqrtf(fabsf(rh)) - sqrtf(fabsf(th));
    float loc = dx * dx + dy * dy + sw * sw + sh * sh;

    float oc = rc - miou;
    oc = oc * oc;

    float no = conf[0] * conf[0] + conf[1] * conf[1];

    float cls = 0.0f;
    #pragma unroll
    for (int k = 0; k < 20; ++k) {
        float d = p[10 + k] - t[5 + k];
        cls += d * d;
    }

    float part = objf * (5.0f * loc + oc + cls) + 0.5f * noobjf * no;

    // ---- block reduce (2 waves), one plain store per block ----
    #pragma unroll
    for (int off = 32; off > 0; off >>= 1)
        part += __shfl_down(part, off, 64);

    __shared__ float ws[2];
    if (lane == 0) ws[wid] = part;
    __syncthreads();
    if (tid == 0)
        partials[blockIdx.x] = ws[0] + ws[1];
}

__global__ __launch_bounds__(256) void yolo_final_kernel(
    const float* __restrict__ partials,
    float* __restrict__ out, float invN)
{
    const int tid = threadIdx.x;
    const float4* p4 = (const float4*)partials;   // 3136/4 = 784 float4
    float s = 0.0f;
    #pragma unroll
    for (int k = 0; k < 4; ++k) {                 // 4*256 = 1024 >= 784
        int i = tid + k * 256;
        if (i < 784) {
            float4 v = p4[i];
            s += (v.x + v.y) + (v.z + v.w);
        }
    }
    #pragma unroll
    for (int off = 32; off > 0; off >>= 1)
        s += __shfl_down(s, off, 64);
    __shared__ float ws[4];
    int lane = tid & 63, wid = tid >> 6;
    if (lane == 0) ws[wid] = s;
    __syncthreads();
    if (tid == 0)
        out[0] = (ws[0] + ws[1] + ws[2] + ws[3]) * invN;
}

extern "C" void kernel_launch(void* const* d_in, const int* in_sizes, int n_in,
                              void* d_out, int out_size, void* d_ws, size_t ws_size,
                              hipStream_t stream) {
    const float* pred = (const float*)d_in[0];
    const float* tgt  = (const float*)d_in[1];
    float* out = (float*)d_out;
    float* partials = (float*)d_ws;        // 3136 f32, fully overwritten

    yolo_partial_kernel<<<NCHUNKS, TPB, 0, stream>>>(pred, tgt, partials);
    yolo_final_kernel<<<1, 256, 0, stream>>>(partials, out, 1.0f / (float)NBATCH);
}